// Round 10
// baseline (75.818 us; speedup 1.0000x reference)
//
#include <hip/hip_runtime.h>
#include <hip/hip_bf16.h>

#define NCLU 32
#define NDIM 16
#define W_VAR 3.0f
#define W_DIST 1.0f
#define W_REG 0.001f
#define W_SMOOTH 5.0f
#define W_SEED 5.0f

#define NBS 512                 // k_seg blocks
#define NBM 1024                // k_main blocks
#define SEG_STRIDE 640          // floats per k_seg block partial slice (608 used)
#define PST     (NBS * SEG_STRIDE)
#define G_CM    (PST)           // 512 floats: cluster means
#define G_M2    (PST + 512)     // 32: |mean|^2
#define G_IV    (PST + 544)     // 32: +1/(2 var)
#define G_SMALL (PST + 576)     // 1: dist+reg+smooth (weighted)
#define PMAIN   (PST + 1280)    // float2[NBM] main partials

typedef __attribute__((ext_vector_type(8)))  short short8v;
typedef __attribute__((ext_vector_type(16))) float f32x16;

__device__ __forceinline__ short f2bf_rz(float x) {
    return (short)(__float_as_uint(x) >> 16);
}
__device__ __forceinline__ unsigned f2bf_rn_u(float x) {
    unsigned u = __float_as_uint(x);
    u += 0x7FFF + ((u >> 16) & 1);
    return u >> 16;
}

union BPack { short8v s8; unsigned u4[4]; __hip_bfloat162 h[4]; };

// ---------------- k_seg: segment sums as MFMA GEMM  S = V^T x Y ----------------
#define NW 4
__global__ __launch_bounds__(256)
void k_seg(const float* __restrict__ feat, const float* __restrict__ sd,
           const int* __restrict__ lab, float* __restrict__ ws, int n)
{
    __shared__ short sm[NW * 4096];   // per wave: [0,2048) V^T, [2048,4096) Y^T
    int tid = threadIdx.x, wid = tid >> 6, lane = tid & 63;
    short* vt = sm + wid * 4096;
    short* yt = vt + 2048;
    int h0 = lane >> 5, m = lane & 31;
    int rowm = m * 64;
    int csig = (lane & 0x33) | ((lane & 4) << 1) | ((lane & 8) >> 1);

    {
        int4 z = {0, 0, 0, 0};
        int4* yz = (int4*)yt;
        yz[lane] = z; yz[lane + 64] = z; yz[lane + 128] = z; yz[lane + 192] = z;
        vt[18 * 64 + (csig ^ ((18 & 7) << 3))] = (short)0x3F80;
    }

    f32x16 acc = {};
    int nwin = (n + 63) >> 6;
    int wslot = blockIdx.x * NW + wid, nws = gridDim.x * NW;
    int prev = -1;

    for (int w = wslot; w < nwin; w += nws) {
        int p = w * 64 + lane;
        bool ok = (p < n);
        size_t pc = ok ? (size_t)p : (size_t)(n - 1);
        const float4* fp = (const float4*)(feat + pc * NDIM);
        float4 f0 = fp[0], f1 = fp[1], f2 = fp[2], f3 = fp[3];
        float sy = sd[2 * pc + 1];
        int lb = lab[pc];
        float v = __expf(sy);

        if (prev >= 0) yt[prev * 64 + (csig ^ ((prev & 7) << 3))] = 0;
        if (ok)        yt[lb * 64 + (csig ^ ((lb & 7) << 3))] = (short)0x3F80;
        prev = ok ? lb : -1;

        float ff[16] = { f0.x,f0.y,f0.z,f0.w, f1.x,f1.y,f1.z,f1.w,
                         f2.x,f2.y,f2.z,f2.w, f3.x,f3.y,f3.z,f3.w };
        #pragma unroll
        for (int j = 0; j < 16; ++j)
            vt[j * 64 + (csig ^ ((j & 7) << 3))] = f2bf_rz(ff[j]);
        vt[16 * 64 + (csig ^ ((16 & 7) << 3))] = (short)f2bf_rn_u(v);
        vt[17 * 64 + (csig ^ ((17 & 7) << 3))] = (short)f2bf_rn_u(v * v);

        #pragma unroll
        for (int q = 0; q < 4; ++q) {
            int o = rowm + ((8 * h0 + 16 * q) ^ ((m & 7) << 3));
            short8v A = *(short8v*)(vt + o);
            short8v B = *(short8v*)(yt + o);
            acc = __builtin_amdgcn_mfma_f32_32x32x16_bf16(A, B, acc, 0, 0, 0);
        }
    }

    __syncthreads();
    float* fsm = (float*)sm;   // [wid][lane][16]
    #pragma unroll
    for (int r = 0; r < 16; ++r) fsm[wid * 1024 + lane * 16 + r] = acc[r];
    __syncthreads();
    for (int o = tid; o < NCLU * 19; o += 256) {
        int c = o / 19, j = o % 19;
        int hh = (j >> 2) & 1, r = (j & 3) + 4 * (j >> 3);
        int ln = c + 32 * hh;
        float s = 0.f;
        #pragma unroll
        for (int ww = 0; ww < NW; ++ww) s += fsm[ww * 1024 + ln * 16 + r];
        ws[(size_t)blockIdx.x * SEG_STRIDE + o] = s;
    }
}

// ---------------- k_redstats: reduce partials + cluster stats ----------------
__global__ __launch_bounds__(1024)
void k_redstats(float* __restrict__ ws)
{
    __shared__ float sums[NCLU * 19];
    __shared__ float s_cm[NCLU * NDIM];
    __shared__ float red[1024];
    int tid = threadIdx.x;

    if (tid < NCLU * 19) {
        float s = 0.f;
        #pragma unroll 8
        for (int b = 0; b < NBS; ++b) s += ws[(size_t)b * SEG_STRIDE + tid];
        sums[tid] = s;
    }
    __syncthreads();

    float contrib = 0.f;
    if (tid < NCLU) {
        int c = tid;
        float cnt = sums[c * 19 + 18];
        float inv = 1.0f / cnt;
        float var = sums[c * 19 + 16] * inv;
        float smo = sums[c * 19 + 17] * inv - var * var;   // mean((v-var)^2)
        float m2 = 0.f;
        for (int d = 0; d < NDIM; ++d) {
            float cm = sums[c * 19 + d] * inv;
            ws[G_CM + c * NDIM + d] = cm;
            s_cm[c * NDIM + d] = cm;
            m2 = fmaf(cm, cm, m2);
        }
        ws[G_M2 + c] = m2;
        ws[G_IV + c] = 0.5f / var;
        contrib = W_REG * sqrtf(m2) * (1.0f / NCLU) + W_SMOOTH * smo * (1.0f / NCLU);
    }
    __syncthreads();
    int i = tid >> 5, j = tid & 31;
    if (i != j) {
        float d2 = 0.f;
        for (int d = 0; d < NDIM; ++d) {
            float df = s_cm[i * NDIM + d] - s_cm[j * NDIM + d];
            d2 = fmaf(df, df, d2);
        }
        float dd = sqrtf(d2);
        float h = fmaxf(3.0f - dd, 0.f);   // 2*DELTA_DIST
        contrib += W_DIST * h * h * (1.0f / ((NCLU - 1) * NCLU));
    }
    red[tid] = contrib;
    __syncthreads();
    for (int s = 512; s > 0; s >>= 1) {
        if (tid < s) red[tid] += red[tid + s];
        __syncthreads();
    }
    if (tid == 0) ws[G_SMALL] = red[0];
}

// ---------------- k_main: BCE + seed. q2 via augmented MFMA, lane-local -------
// A1 row c: -2*s_c*cm[c][d] (s_c = iv_c*log2e).
// A2 row c: h0=0 k-slots [m2_c*s_c, s_c], h0=1 k-slots [s_c, 0].
// B1 col p: f[p][d].  B2 col p: h0=0 [1, f2_lo], h0=1 [f2_hi, 0]
//   => D[c][p] = s_c*(m2 + f2_lo + f2_hi) - 2 s_c dot = q2 (log2 units).
// No cross-lane ops at all. 2-deep software pipeline over 32-pt tiles.
__global__ __launch_bounds__(256, 4)
void k_main(const float* __restrict__ feat, const float* __restrict__ sd,
            const int* __restrict__ lab, float* __restrict__ ws, int n)
{
    int tid = threadIdx.x, wid = tid >> 6, lane = tid & 63;
    int h0 = lane >> 5, pl = lane & 31;

    // loop-invariant A fragments (per lane: cluster row m = pl)
    float iv = ws[G_IV + pl];
    float sc = iv * 1.44269504f;           // log2e / (2 var)
    float m2 = ws[G_M2 + pl];
    const float* cmrow = ws + G_CM + pl * NDIM + 4 * h0;
    float4 ca = *(const float4*)(cmrow);
    float4 cb = *(const float4*)(cmrow + 8);
    float t2s = -2.0f * sc;
    BPack a1;
    a1.u4[0] = f2bf_rn_u(ca.x * t2s) | (f2bf_rn_u(ca.y * t2s) << 16);
    a1.u4[1] = f2bf_rn_u(ca.z * t2s) | (f2bf_rn_u(ca.w * t2s) << 16);
    a1.u4[2] = f2bf_rn_u(cb.x * t2s) | (f2bf_rn_u(cb.y * t2s) << 16);
    a1.u4[3] = f2bf_rn_u(cb.z * t2s) | (f2bf_rn_u(cb.w * t2s) << 16);
    BPack a2;
    a2.u4[0] = (h0 == 0) ? (f2bf_rn_u(m2 * sc) | (f2bf_rn_u(sc) << 16))
                         : f2bf_rn_u(sc);
    a2.u4[1] = 0u; a2.u4[2] = 0u; a2.u4[3] = 0u;

    float bce = 0.f, sl = 0.f;
    int nt = (n + 31) >> 5;
    int slot = blockIdx.x * 4 + wid, nslots = gridDim.x * 4;

    int t = slot;
    bool live = (t < nt);
    float4 fa = {}, fb = {};
    int lb = 0; float s0 = 0.f;
    if (live) {
        size_t pc = (size_t)t * 32 + pl;
        if (pc >= (size_t)n) pc = n - 1;
        const float* fr = feat + pc * NDIM + 4 * h0;
        fa = *(const float4*)fr;
        fb = *(const float4*)(fr + 8);
        lb = lab[pc];
        s0 = sd[2 * pc];
    }

    while (live) {
        // ---- issue next tile's loads (overlap with compute below) ----
        int tn = t + nslots;
        bool nlive = (tn < nt);
        int tc = nlive ? tn : 0;
        size_t npc = (size_t)tc * 32 + pl;
        if (npc >= (size_t)n) npc = n - 1;
        const float* nfr = feat + npc * NDIM + 4 * h0;
        float4 nfa = *(const float4*)nfr;
        float4 nfb = *(const float4*)(nfr + 8);
        int nlb = lab[npc];
        float ns0 = sd[2 * npc];

        // ---- compute current tile ----
        // f2 half-sum (tree)
        float d0 = fmaf(fa.y, fa.y, fa.x * fa.x);
        float d1 = fmaf(fa.w, fa.w, fa.z * fa.z);
        float d2 = fmaf(fb.y, fb.y, fb.x * fb.x);
        float d3 = fmaf(fb.w, fb.w, fb.z * fb.z);
        float f2h = (d0 + d1) + (d2 + d3);

        BPack b1;
        float2 q01; q01.x = fa.x; q01.y = fa.y;
        float2 q23; q23.x = fa.z; q23.y = fa.w;
        float2 q45; q45.x = fb.x; q45.y = fb.y;
        float2 q67; q67.x = fb.z; q67.y = fb.w;
        b1.h[0] = __float22bfloat162_rn(q01);
        b1.h[1] = __float22bfloat162_rn(q23);
        b1.h[2] = __float22bfloat162_rn(q45);
        b1.h[3] = __float22bfloat162_rn(q67);
        BPack b2;
        unsigned pk = f2bf_rn_u(f2h);
        b2.u4[0] = (h0 == 0) ? (0x3F80u | (pk << 16)) : pk;
        b2.u4[1] = 0u; b2.u4[2] = 0u; b2.u4[3] = 0u;

        f32x16 dz = {};
        f32x16 D = __builtin_amdgcn_mfma_f32_32x32x16_bf16(a1.s8, b1.s8, dz, 0, 0, 0);
        D = __builtin_amdgcn_mfma_f32_32x32x16_bf16(a2.s8, b2.s8, D, 0, 0, 0);

        int p = t * 32 + pl;
        bool ok = (p < n);
        int lb4 = lb - 4 * h0;     // own iff lb4 == CR=(r&3)+8*(r>>2)
        unsigned ulb4 = (unsigned)lb4;
        bool hasown = (ulb4 < 32u) && ((ulb4 & 4u) == 0u);
        float bce_t = 0.f, ownP = 0.f;
        #pragma unroll
        for (int r = 0; r < 16; ++r) {
            const int CR = (r & 3) + 8 * (r >> 2);
            float q2 = fmaxf(D[r], 0.f);
            float P = __builtin_amdgcn_exp2f(-q2);
            float s = fmaf(P, 0.25f, 0.33333333f);
            s = fmaf(P, s, 0.5f);
            float ser = fmaf(P * P, s, P);
            float tl = -__logf(1.0f - P);
            float ts = (P > 0.5f) ? tl : ser;
            bool own = (lb4 == CR);
            float contrib = fminf(own ? q2 * 0.69314718f : ts, 100.f);
            bce_t += contrib;
            ownP = own ? P : ownP;
        }
        float mask = ok ? 1.f : 0.f;
        bce = fmaf(mask, bce_t, bce);
        float e = ownP - s0;
        float smk = hasown ? mask : 0.f;
        sl = fmaf(smk * e, e, sl);

        // ---- rotate pipeline ----
        fa = nfa; fb = nfb; lb = nlb; s0 = ns0;
        t = tn; live = nlive;
    }

    __shared__ float rb[256], rsd[256];
    rb[tid] = bce; rsd[tid] = sl;
    __syncthreads();
    for (int s = 128; s > 0; s >>= 1) {
        if (tid < s) { rb[tid] += rb[tid + s]; rsd[tid] += rsd[tid + s]; }
        __syncthreads();
    }
    if (tid == 0) {
        float2 pr; pr.x = rb[0]; pr.y = rsd[0];
        ((float2*)(ws + PMAIN))[blockIdx.x] = pr;
    }
}

__global__ __launch_bounds__(512)
void k_final(const float* __restrict__ ws, float* __restrict__ out, int n)
{
    __shared__ float rb[512], rs[512];
    int tid = threadIdx.x;
    float2 p0 = ((const float2*)(ws + PMAIN))[tid];
    float2 p1 = ((const float2*)(ws + PMAIN))[tid + 512];
    rb[tid] = p0.x + p1.x; rs[tid] = p0.y + p1.y;
    __syncthreads();
    for (int s = 256; s > 0; s >>= 1) {
        if (tid < s) { rb[tid] += rb[tid + s]; rs[tid] += rs[tid + s]; }
        __syncthreads();
    }
    if (tid == 0) {
        float var_loss  = rb[0] / ((float)n * (float)NCLU);
        float seed_loss = rs[0] / (float)n;
        out[0] = W_VAR * var_loss + ws[G_SMALL] + W_SEED * seed_loss;
    }
}

extern "C" void kernel_launch(void* const* d_in, const int* in_sizes, int n_in,
                              void* d_out, int out_size, void* d_ws, size_t ws_size,
                              hipStream_t stream)
{
    const float* feat = (const float*)d_in[0];
    const float* sd   = (const float*)d_in[1];
    const int*   lab  = (const int*)d_in[2];
    float* ws = (float*)d_ws;
    int n = in_sizes[2];

    k_seg     <<<NBS, 256,  0, stream>>>(feat, sd, lab, ws, n);
    k_redstats<<<1,   1024, 0, stream>>>(ws);
    k_main    <<<NBM, 256,  0, stream>>>(feat, sd, lab, ws, n);
    k_final   <<<1,   512,  0, stream>>>(ws, (float*)d_out, n);
}

// Round 11
// 45.661 us; speedup vs baseline: 1.6604x; 1.6604x over previous
//
#include <hip/hip_runtime.h>
#include <hip/hip_bf16.h>

#define NCLU 32
#define NDIM 16
#define W_VAR 3.0f
#define W_DIST 1.0f
#define W_REG 0.001f
#define W_SMOOTH 5.0f
#define W_SEED 5.0f

#define NBS 512                 // k_seg blocks
#define NBM 2048                // k_main blocks
#define SEG_STRIDE 640          // floats per k_seg block partial slice (608 used)
#define PST     (NBS * SEG_STRIDE)
#define G_CM    (PST)           // 512 floats: cluster means
#define G_M2    (PST + 512)     // 32: |mean|^2
#define G_IV    (PST + 544)     // 32: +1/(2 var)
#define G_SMALL (PST + 576)     // 1: dist+reg+smooth (weighted)
#define G_SUMS  (PST + 608)     // 608: reduced segment sums
#define PMAIN   (PST + 1280)    // float2[NBM] main partials

typedef __attribute__((ext_vector_type(8)))  short short8v;
typedef __attribute__((ext_vector_type(16))) float f32x16;

__device__ __forceinline__ short f2bf_rz(float x) {
    return (short)(__float_as_uint(x) >> 16);
}
__device__ __forceinline__ unsigned f2bf_rn_u(float x) {
    unsigned u = __float_as_uint(x);
    u += 0x7FFF + ((u >> 16) & 1);
    return u >> 16;
}

union BPack { short8v s8; unsigned u4[4]; __hip_bfloat162 h[4]; };

// ---------------- k_seg: segment sums as MFMA GEMM  S = V^T x Y ----------------
#define NW 4
__global__ __launch_bounds__(256)
void k_seg(const float* __restrict__ feat, const float* __restrict__ sd,
           const int* __restrict__ lab, float* __restrict__ ws, int n)
{
    __shared__ short sm[NW * 4096];   // per wave: [0,2048) V^T, [2048,4096) Y^T
    int tid = threadIdx.x, wid = tid >> 6, lane = tid & 63;
    short* vt = sm + wid * 4096;
    short* yt = vt + 2048;
    int h0 = lane >> 5, m = lane & 31;
    int rowm = m * 64;
    int csig = (lane & 0x33) | ((lane & 4) << 1) | ((lane & 8) >> 1);

    {
        int4 z = {0, 0, 0, 0};
        int4* yz = (int4*)yt;
        yz[lane] = z; yz[lane + 64] = z; yz[lane + 128] = z; yz[lane + 192] = z;
        vt[18 * 64 + (csig ^ ((18 & 7) << 3))] = (short)0x3F80;
    }

    f32x16 acc = {};
    int nwin = (n + 63) >> 6;
    int wslot = blockIdx.x * NW + wid, nws = gridDim.x * NW;
    int prev = -1;

    for (int w = wslot; w < nwin; w += nws) {
        int p = w * 64 + lane;
        bool ok = (p < n);
        size_t pc = ok ? (size_t)p : (size_t)(n - 1);
        const float4* fp = (const float4*)(feat + pc * NDIM);
        float4 f0 = fp[0], f1 = fp[1], f2 = fp[2], f3 = fp[3];
        float sy = sd[2 * pc + 1];
        int lb = lab[pc];
        float v = __expf(sy);

        if (prev >= 0) yt[prev * 64 + (csig ^ ((prev & 7) << 3))] = 0;
        if (ok)        yt[lb * 64 + (csig ^ ((lb & 7) << 3))] = (short)0x3F80;
        prev = ok ? lb : -1;

        float ff[16] = { f0.x,f0.y,f0.z,f0.w, f1.x,f1.y,f1.z,f1.w,
                         f2.x,f2.y,f2.z,f2.w, f3.x,f3.y,f3.z,f3.w };
        #pragma unroll
        for (int j = 0; j < 16; ++j)
            vt[j * 64 + (csig ^ ((j & 7) << 3))] = f2bf_rz(ff[j]);
        vt[16 * 64 + (csig ^ ((16 & 7) << 3))] = (short)f2bf_rn_u(v);
        vt[17 * 64 + (csig ^ ((17 & 7) << 3))] = (short)f2bf_rn_u(v * v);

        #pragma unroll
        for (int q = 0; q < 4; ++q) {
            int o = rowm + ((8 * h0 + 16 * q) ^ ((m & 7) << 3));
            short8v A = *(short8v*)(vt + o);
            short8v B = *(short8v*)(yt + o);
            acc = __builtin_amdgcn_mfma_f32_32x32x16_bf16(A, B, acc, 0, 0, 0);
        }
    }

    __syncthreads();
    float* fsm = (float*)sm;   // [wid][lane][16]
    #pragma unroll
    for (int r = 0; r < 16; ++r) fsm[wid * 1024 + lane * 16 + r] = acc[r];
    __syncthreads();
    for (int o = tid; o < NCLU * 19; o += 256) {
        int c = o / 19, j = o % 19;
        int hh = (j >> 2) & 1, r = (j & 3) + 4 * (j >> 3);
        int ln = c + 32 * hh;
        float s = 0.f;
        #pragma unroll
        for (int ww = 0; ww < NW; ++ww) s += fsm[ww * 1024 + ln * 16 + r];
        ws[(size_t)blockIdx.x * SEG_STRIDE + o] = s;
    }
}

// ---------------- k_red1: parallel reduce of per-block partials ----------------
__global__ __launch_bounds__(256)
void k_red1(float* __restrict__ ws)
{
    __shared__ float red[256];
    int tid = threadIdx.x;
    int o = blockIdx.x * 4 + (tid & 3);    // 152 blocks x 4 outputs = 608
    int brow = tid >> 2;                   // 64 rows
    float s = 0.f;
    #pragma unroll
    for (int k = 0; k < 8; ++k)
        s += ws[(size_t)(brow + 64 * k) * SEG_STRIDE + o];
    red[tid] = s;
    __syncthreads();
    for (int st = 128; st >= 4; st >>= 1) {
        if (tid < st) red[tid] += red[tid + st];
        __syncthreads();
    }
    if (tid < 4) ws[G_SUMS + blockIdx.x * 4 + tid] = red[tid];
}

// ---------------- k_stats: cluster stats + small losses ----------------
__global__ __launch_bounds__(1024)
void k_stats(float* __restrict__ ws)
{
    __shared__ float sums[NCLU * 19];
    __shared__ float s_cm[NCLU * NDIM];
    __shared__ float red[1024];
    int tid = threadIdx.x;
    if (tid < NCLU * 19) sums[tid] = ws[G_SUMS + tid];
    __syncthreads();

    float contrib = 0.f;
    if (tid < NCLU) {
        int c = tid;
        float cnt = sums[c * 19 + 18];
        float inv = 1.0f / cnt;
        float var = sums[c * 19 + 16] * inv;
        float smo = sums[c * 19 + 17] * inv - var * var;   // mean((v-var)^2)
        float m2 = 0.f;
        for (int d = 0; d < NDIM; ++d) {
            float cm = sums[c * 19 + d] * inv;
            ws[G_CM + c * NDIM + d] = cm;
            s_cm[c * NDIM + d] = cm;
            m2 = fmaf(cm, cm, m2);
        }
        ws[G_M2 + c] = m2;
        ws[G_IV + c] = 0.5f / var;
        contrib = W_REG * sqrtf(m2) * (1.0f / NCLU) + W_SMOOTH * smo * (1.0f / NCLU);
    }
    __syncthreads();
    int i = tid >> 5, j = tid & 31;
    if (i != j) {
        float d2 = 0.f;
        for (int d = 0; d < NDIM; ++d) {
            float df = s_cm[i * NDIM + d] - s_cm[j * NDIM + d];
            d2 = fmaf(df, df, d2);
        }
        float dd = sqrtf(d2);
        float h = fmaxf(3.0f - dd, 0.f);   // 2*DELTA_DIST
        contrib += W_DIST * h * h * (1.0f / ((NCLU - 1) * NCLU));
    }
    red[tid] = contrib;
    __syncthreads();
    for (int s = 512; s > 0; s >>= 1) {
        if (tid < s) red[tid] += red[tid + s];
        __syncthreads();
    }
    if (tid == 0) ws[G_SMALL] = red[0];
}

// ---------------- k_main: BCE + seed. q2 via augmented MFMA, lane-local -------
// A1 row c: -2*s_c*cm[c][d] (s_c = iv_c*log2e).
// A2 row c: h0=0 k-slots [m2_c*s_c, s_c], h0=1 k-slots [s_c, 0].
// B1 col p: f[p][d].  B2 col p: h0=0 [1, f2_lo], h0=1 [f2_hi, 0]
//   => D[c][p] = q2 (log2 units), all lane-local.
// Epilogue: 4-term series only (valid P<=0.7, err<0.09 << 0.25/term budget);
// rare wave-branch exact fixup when any P>0.7. Own-cluster corr. once per tile.
__global__ __launch_bounds__(256, 4)
void k_main(const float* __restrict__ feat, const float* __restrict__ sd,
            const int* __restrict__ lab, float* __restrict__ ws, int n)
{
    int tid = threadIdx.x, wid = tid >> 6, lane = tid & 63;
    int h0 = lane >> 5, pl = lane & 31;

    float iv = ws[G_IV + pl];
    float sc = iv * 1.44269504f;           // log2e / (2 var)
    float m2 = ws[G_M2 + pl];
    const float* cmrow = ws + G_CM + pl * NDIM + 4 * h0;
    float4 ca = *(const float4*)(cmrow);
    float4 cb = *(const float4*)(cmrow + 8);
    float t2s = -2.0f * sc;
    BPack a1;
    a1.u4[0] = f2bf_rn_u(ca.x * t2s) | (f2bf_rn_u(ca.y * t2s) << 16);
    a1.u4[1] = f2bf_rn_u(ca.z * t2s) | (f2bf_rn_u(ca.w * t2s) << 16);
    a1.u4[2] = f2bf_rn_u(cb.x * t2s) | (f2bf_rn_u(cb.y * t2s) << 16);
    a1.u4[3] = f2bf_rn_u(cb.z * t2s) | (f2bf_rn_u(cb.w * t2s) << 16);
    BPack a2;
    a2.u4[0] = (h0 == 0) ? (f2bf_rn_u(m2 * sc) | (f2bf_rn_u(sc) << 16))
                         : f2bf_rn_u(sc);
    a2.u4[1] = 0u; a2.u4[2] = 0u; a2.u4[3] = 0u;

    float bce = 0.f, sl = 0.f;
    int nt = (n + 31) >> 5;
    int slot = blockIdx.x * 4 + wid, nslots = gridDim.x * 4;

    for (int t = slot; t < nt; t += nslots) {
        int p = t * 32 + pl;
        bool ok = (p < n);
        size_t pc = ok ? (size_t)p : (size_t)(n - 1);
        const float* fr = feat + pc * NDIM + 4 * h0;
        float4 fa = *(const float4*)fr;
        float4 fb = *(const float4*)(fr + 8);
        int lb = lab[pc];
        float s0 = sd[2 * pc];

        float d0 = fmaf(fa.y, fa.y, fa.x * fa.x);
        float d1 = fmaf(fa.w, fa.w, fa.z * fa.z);
        float d2 = fmaf(fb.y, fb.y, fb.x * fb.x);
        float d3 = fmaf(fb.w, fb.w, fb.z * fb.z);
        float f2h = (d0 + d1) + (d2 + d3);

        BPack b1;
        float2 q01; q01.x = fa.x; q01.y = fa.y;
        float2 q23; q23.x = fa.z; q23.y = fa.w;
        float2 q45; q45.x = fb.x; q45.y = fb.y;
        float2 q67; q67.x = fb.z; q67.y = fb.w;
        b1.h[0] = __float22bfloat162_rn(q01);
        b1.h[1] = __float22bfloat162_rn(q23);
        b1.h[2] = __float22bfloat162_rn(q45);
        b1.h[3] = __float22bfloat162_rn(q67);
        BPack b2;
        unsigned pk = f2bf_rn_u(f2h);
        b2.u4[0] = (h0 == 0) ? (0x3F80u | (pk << 16)) : pk;
        b2.u4[1] = 0u; b2.u4[2] = 0u; b2.u4[3] = 0u;

        f32x16 dz = {};
        f32x16 D = __builtin_amdgcn_mfma_f32_32x32x16_bf16(a1.s8, b1.s8, dz, 0, 0, 0);
        D = __builtin_amdgcn_mfma_f32_32x32x16_bf16(a2.s8, b2.s8, D, 0, 0, 0);

        int lb4 = lb - 4 * h0;     // own iff lb4 == CR=(r&3)+8*(r>>2)
        unsigned ulb4 = (unsigned)lb4;
        bool hasown = (ulb4 < 32u) && ((ulb4 & 4u) == 0u);

        float bce_t = 0.f, ownP = 0.f, ownQ = 0.f, pmax = 0.f;
        #pragma unroll
        for (int r = 0; r < 16; ++r) {
            const int CR = (r & 3) + 8 * (r >> 2);
            float q2 = fmaxf(D[r], 0.f);
            float P = __builtin_amdgcn_exp2f(-q2);
            float s = fmaf(P, 0.25f, 0.33333333f);
            s = fmaf(P, s, 0.5f);
            float ser = fmaf(P * P, s, P);
            bce_t += ser;
            pmax = fmaxf(pmax, P);
            bool own = (lb4 == CR);
            ownP = own ? P : ownP;
            ownQ = own ? q2 : ownQ;
        }
        // own-cluster correction: replace its series term with clamped q-term
        float so = fmaf(ownP, 0.25f, 0.33333333f);
        so = fmaf(ownP, so, 0.5f);
        float sero = fmaf(ownP * ownP, so, ownP);
        float ocorr = fminf(ownQ * 0.69314718f, 100.f) - sero;
        bce_t += hasown ? ocorr : 0.f;

        // rare exact path (any P near 1): recompute tile with true log
        if (__any(pmax > 0.70f)) {
            bce_t = 0.f;
            #pragma unroll
            for (int r = 0; r < 16; ++r) {
                const int CR = (r & 3) + 8 * (r >> 2);
                float q2 = fmaxf(D[r], 0.f);
                float P = __builtin_amdgcn_exp2f(-q2);
                float tw = fminf(-__logf(1.0f - P), 100.f);
                float to = fminf(q2 * 0.69314718f, 100.f);
                bce_t += (lb4 == CR) ? to : tw;
            }
        }

        float mask = ok ? 1.f : 0.f;
        bce = fmaf(mask, bce_t, bce);
        float e = ownP - s0;
        float smk = hasown ? mask : 0.f;
        sl = fmaf(smk * e, e, sl);
    }

    __shared__ float rb[256], rsd[256];
    rb[tid] = bce; rsd[tid] = sl;
    __syncthreads();
    for (int s = 128; s > 0; s >>= 1) {
        if (tid < s) { rb[tid] += rb[tid + s]; rsd[tid] += rsd[tid + s]; }
        __syncthreads();
    }
    if (tid == 0) {
        float2 pr; pr.x = rb[0]; pr.y = rsd[0];
        ((float2*)(ws + PMAIN))[blockIdx.x] = pr;
    }
}

__global__ __launch_bounds__(1024)
void k_final(const float* __restrict__ ws, float* __restrict__ out, int n)
{
    __shared__ float rb[1024], rs[1024];
    int tid = threadIdx.x;
    float2 p0 = ((const float2*)(ws + PMAIN))[tid];
    float2 p1 = ((const float2*)(ws + PMAIN))[tid + 1024];
    rb[tid] = p0.x + p1.x; rs[tid] = p0.y + p1.y;
    __syncthreads();
    for (int s = 512; s > 0; s >>= 1) {
        if (tid < s) { rb[tid] += rb[tid + s]; rs[tid] += rs[tid + s]; }
        __syncthreads();
    }
    if (tid == 0) {
        float var_loss  = rb[0] / ((float)n * (float)NCLU);
        float seed_loss = rs[0] / (float)n;
        out[0] = W_VAR * var_loss + ws[G_SMALL] + W_SEED * seed_loss;
    }
}

extern "C" void kernel_launch(void* const* d_in, const int* in_sizes, int n_in,
                              void* d_out, int out_size, void* d_ws, size_t ws_size,
                              hipStream_t stream)
{
    const float* feat = (const float*)d_in[0];
    const float* sd   = (const float*)d_in[1];
    const int*   lab  = (const int*)d_in[2];
    float* ws = (float*)d_ws;
    int n = in_sizes[2];

    k_seg  <<<NBS, 256,  0, stream>>>(feat, sd, lab, ws, n);
    k_red1 <<<152, 256,  0, stream>>>(ws);
    k_stats<<<1,   1024, 0, stream>>>(ws);
    k_main <<<NBM, 256,  0, stream>>>(feat, sd, lab, ws, n);
    k_final<<<1,   1024, 0, stream>>>(ws, (float*)d_out, n);
}

// Round 12
// 44.210 us; speedup vs baseline: 1.7150x; 1.0328x over previous
//
#include <hip/hip_runtime.h>
#include <hip/hip_bf16.h>

#define NCLU 32
#define NDIM 16
#define W_VAR 3.0f
#define W_DIST 1.0f
#define W_REG 0.001f
#define W_SMOOTH 5.0f
#define W_SEED 5.0f

#define NBS 512                 // k_seg blocks
#define NBM 2048                // k_main blocks
#define SEG_STRIDE 640          // floats per k_seg block partial slice (608 used)
#define PST     (NBS * SEG_STRIDE)
#define G_CM    (PST)           // 512 floats: cluster means
#define G_M2    (PST + 512)     // 32: |mean|^2
#define G_IV    (PST + 544)     // 32: +1/(2 var)
#define G_SMALL (PST + 576)     // 1: dist+reg+smooth (weighted)
#define G_SUMS  (PST + 608)     // 608: reduced segment sums
#define PMAIN   (PST + 1280)    // float2[NBM] main partials

typedef __attribute__((ext_vector_type(8)))  short short8v;
typedef __attribute__((ext_vector_type(16))) float f32x16;

__device__ __forceinline__ short f2bf_rz(float x) {
    return (short)(__float_as_uint(x) >> 16);
}
__device__ __forceinline__ unsigned f2bf_rn_u(float x) {
    unsigned u = __float_as_uint(x);
    u += 0x7FFF + ((u >> 16) & 1);
    return u >> 16;
}

union BPack { short8v s8; unsigned u4[4]; __hip_bfloat162 h[4]; };

// ---------------- k_seg: segment sums as MFMA GEMM  S = V^T x Y ----------------
#define NW 4
__global__ __launch_bounds__(256)
void k_seg(const float* __restrict__ feat, const float* __restrict__ sd,
           const int* __restrict__ lab, float* __restrict__ ws, int n)
{
    __shared__ short sm[NW * 4096];   // per wave: [0,2048) V^T, [2048,4096) Y^T
    int tid = threadIdx.x, wid = tid >> 6, lane = tid & 63;
    short* vt = sm + wid * 4096;
    short* yt = vt + 2048;
    int h0 = lane >> 5, m = lane & 31;
    int rowm = m * 64;
    int csig = (lane & 0x33) | ((lane & 4) << 1) | ((lane & 8) >> 1);

    {
        int4 z = {0, 0, 0, 0};
        int4* yz = (int4*)yt;
        yz[lane] = z; yz[lane + 64] = z; yz[lane + 128] = z; yz[lane + 192] = z;
        vt[18 * 64 + (csig ^ ((18 & 7) << 3))] = (short)0x3F80;
    }

    f32x16 acc = {};
    int nwin = (n + 63) >> 6;
    int wslot = blockIdx.x * NW + wid, nws = gridDim.x * NW;
    int prev = -1;

    for (int w = wslot; w < nwin; w += nws) {
        int p = w * 64 + lane;
        bool ok = (p < n);
        size_t pc = ok ? (size_t)p : (size_t)(n - 1);
        const float4* fp = (const float4*)(feat + pc * NDIM);
        float4 f0 = fp[0], f1 = fp[1], f2 = fp[2], f3 = fp[3];
        float sy = sd[2 * pc + 1];
        int lb = lab[pc];
        float v = __expf(sy);

        if (prev >= 0) yt[prev * 64 + (csig ^ ((prev & 7) << 3))] = 0;
        if (ok)        yt[lb * 64 + (csig ^ ((lb & 7) << 3))] = (short)0x3F80;
        prev = ok ? lb : -1;

        float ff[16] = { f0.x,f0.y,f0.z,f0.w, f1.x,f1.y,f1.z,f1.w,
                         f2.x,f2.y,f2.z,f2.w, f3.x,f3.y,f3.z,f3.w };
        #pragma unroll
        for (int j = 0; j < 16; ++j)
            vt[j * 64 + (csig ^ ((j & 7) << 3))] = f2bf_rz(ff[j]);
        vt[16 * 64 + (csig ^ ((16 & 7) << 3))] = (short)f2bf_rn_u(v);
        vt[17 * 64 + (csig ^ ((17 & 7) << 3))] = (short)f2bf_rn_u(v * v);

        #pragma unroll
        for (int q = 0; q < 4; ++q) {
            int o = rowm + ((8 * h0 + 16 * q) ^ ((m & 7) << 3));
            short8v A = *(short8v*)(vt + o);
            short8v B = *(short8v*)(yt + o);
            acc = __builtin_amdgcn_mfma_f32_32x32x16_bf16(A, B, acc, 0, 0, 0);
        }
    }

    __syncthreads();
    float* fsm = (float*)sm;   // [wid][lane][16]
    #pragma unroll
    for (int r = 0; r < 16; ++r) fsm[wid * 1024 + lane * 16 + r] = acc[r];
    __syncthreads();
    for (int o = tid; o < NCLU * 19; o += 256) {
        int c = o / 19, j = o % 19;
        int hh = (j >> 2) & 1, r = (j & 3) + 4 * (j >> 3);
        int ln = c + 32 * hh;
        float s = 0.f;
        #pragma unroll
        for (int ww = 0; ww < NW; ++ww) s += fsm[ww * 1024 + ln * 16 + r];
        ws[(size_t)blockIdx.x * SEG_STRIDE + o] = s;
    }
}

// ---------------- k_red1: parallel reduce of per-block partials ----------------
__global__ __launch_bounds__(256)
void k_red1(float* __restrict__ ws)
{
    __shared__ float red[256];
    int tid = threadIdx.x;
    int o = blockIdx.x * 4 + (tid & 3);    // 152 blocks x 4 outputs = 608
    int brow = tid >> 2;                   // 64 rows
    float s = 0.f;
    #pragma unroll
    for (int k = 0; k < 8; ++k)
        s += ws[(size_t)(brow + 64 * k) * SEG_STRIDE + o];
    red[tid] = s;
    __syncthreads();
    for (int st = 128; st >= 4; st >>= 1) {
        if (tid < st) red[tid] += red[tid + st];
        __syncthreads();
    }
    if (tid < 4) ws[G_SUMS + blockIdx.x * 4 + tid] = red[tid];
}

// ---------------- k_stats: cluster stats + small losses ----------------
__global__ __launch_bounds__(1024)
void k_stats(float* __restrict__ ws)
{
    __shared__ float sums[NCLU * 19];
    __shared__ float s_cm[NCLU * NDIM];
    __shared__ float red[1024];
    int tid = threadIdx.x;
    if (tid < NCLU * 19) sums[tid] = ws[G_SUMS + tid];
    __syncthreads();

    float contrib = 0.f;
    if (tid < NCLU) {
        int c = tid;
        float cnt = sums[c * 19 + 18];
        float inv = 1.0f / cnt;
        float var = sums[c * 19 + 16] * inv;
        float smo = sums[c * 19 + 17] * inv - var * var;   // mean((v-var)^2)
        float m2 = 0.f;
        for (int d = 0; d < NDIM; ++d) {
            float cm = sums[c * 19 + d] * inv;
            ws[G_CM + c * NDIM + d] = cm;
            s_cm[c * NDIM + d] = cm;
            m2 = fmaf(cm, cm, m2);
        }
        ws[G_M2 + c] = m2;
        ws[G_IV + c] = 0.5f / var;
        contrib = W_REG * sqrtf(m2) * (1.0f / NCLU) + W_SMOOTH * smo * (1.0f / NCLU);
    }
    __syncthreads();
    int i = tid >> 5, j = tid & 31;
    if (i != j) {
        float d2 = 0.f;
        for (int d = 0; d < NDIM; ++d) {
            float df = s_cm[i * NDIM + d] - s_cm[j * NDIM + d];
            d2 = fmaf(df, df, d2);
        }
        float dd = sqrtf(d2);
        float h = fmaxf(3.0f - dd, 0.f);   // 2*DELTA_DIST
        contrib += W_DIST * h * h * (1.0f / ((NCLU - 1) * NCLU));
    }
    red[tid] = contrib;
    __syncthreads();
    for (int s = 512; s > 0; s >>= 1) {
        if (tid < s) red[tid] += red[tid + s];
        __syncthreads();
    }
    if (tid == 0) ws[G_SMALL] = red[0];
}

// ---------------- k_main: BCE + seed. q2 via augmented MFMA, lane-local -------
// A1 row c: -2*s_c*cm[c][d] (s_c = iv_c*log2e).
// A2 row c: h0=0 k-slots [m2_c*s_c, s_c], h0=1 k-slots [s_c, 0].
// B1 col p: f[p][d].  B2 col p: h0=0 [1, f2_lo], h0=1 [f2_hi, 0]
//   => D[c][p] = q2 (log2 units), all lane-local.
// Epilogue: 3-term series (P<=0.7; err<=P^4/4<0.06 rare, mean budget 0.25);
// own q recovered from ownP via v_log (no per-entry ownQ selects);
// rare wave-branch exact fixup when any P>0.7.
__global__ __launch_bounds__(256, 8)
void k_main(const float* __restrict__ feat, const float* __restrict__ sd,
            const int* __restrict__ lab, float* __restrict__ ws, int n)
{
    int tid = threadIdx.x, wid = tid >> 6, lane = tid & 63;
    int h0 = lane >> 5, pl = lane & 31;

    float iv = ws[G_IV + pl];
    float sc = iv * 1.44269504f;           // log2e / (2 var)
    float m2 = ws[G_M2 + pl];
    const float* cmrow = ws + G_CM + pl * NDIM + 4 * h0;
    float4 ca = *(const float4*)(cmrow);
    float4 cb = *(const float4*)(cmrow + 8);
    float t2s = -2.0f * sc;
    BPack a1;
    a1.u4[0] = f2bf_rn_u(ca.x * t2s) | (f2bf_rn_u(ca.y * t2s) << 16);
    a1.u4[1] = f2bf_rn_u(ca.z * t2s) | (f2bf_rn_u(ca.w * t2s) << 16);
    a1.u4[2] = f2bf_rn_u(cb.x * t2s) | (f2bf_rn_u(cb.y * t2s) << 16);
    a1.u4[3] = f2bf_rn_u(cb.z * t2s) | (f2bf_rn_u(cb.w * t2s) << 16);
    BPack a2;
    a2.u4[0] = (h0 == 0) ? (f2bf_rn_u(m2 * sc) | (f2bf_rn_u(sc) << 16))
                         : f2bf_rn_u(sc);
    a2.u4[1] = 0u; a2.u4[2] = 0u; a2.u4[3] = 0u;

    float bce = 0.f, sl = 0.f;
    int nt = (n + 31) >> 5;
    int slot = blockIdx.x * 4 + wid, nslots = gridDim.x * 4;

    for (int t = slot; t < nt; t += nslots) {
        int p = t * 32 + pl;
        bool ok = (p < n);
        size_t pc = ok ? (size_t)p : (size_t)(n - 1);
        const float* fr = feat + pc * NDIM + 4 * h0;
        float4 fa = *(const float4*)fr;
        float4 fb = *(const float4*)(fr + 8);
        int lb = lab[pc];
        float s0 = sd[2 * pc];

        float d0 = fmaf(fa.y, fa.y, fa.x * fa.x);
        float d1 = fmaf(fa.w, fa.w, fa.z * fa.z);
        float d2 = fmaf(fb.y, fb.y, fb.x * fb.x);
        float d3 = fmaf(fb.w, fb.w, fb.z * fb.z);
        float f2h = (d0 + d1) + (d2 + d3);

        BPack b1;
        float2 q01; q01.x = fa.x; q01.y = fa.y;
        float2 q23; q23.x = fa.z; q23.y = fa.w;
        float2 q45; q45.x = fb.x; q45.y = fb.y;
        float2 q67; q67.x = fb.z; q67.y = fb.w;
        b1.h[0] = __float22bfloat162_rn(q01);
        b1.h[1] = __float22bfloat162_rn(q23);
        b1.h[2] = __float22bfloat162_rn(q45);
        b1.h[3] = __float22bfloat162_rn(q67);
        BPack b2;
        unsigned pk = f2bf_rn_u(f2h);
        b2.u4[0] = (h0 == 0) ? (0x3F80u | (pk << 16)) : pk;
        b2.u4[1] = 0u; b2.u4[2] = 0u; b2.u4[3] = 0u;

        f32x16 dz = {};
        f32x16 D = __builtin_amdgcn_mfma_f32_32x32x16_bf16(a1.s8, b1.s8, dz, 0, 0, 0);
        D = __builtin_amdgcn_mfma_f32_32x32x16_bf16(a2.s8, b2.s8, D, 0, 0, 0);

        int lb4 = lb - 4 * h0;     // own iff lb4 == CR=(r&3)+8*(r>>2)
        unsigned ulb4 = (unsigned)lb4;
        bool hasown = (ulb4 < 32u) && ((ulb4 & 4u) == 0u);

        float bce_t = 0.f, ownP = 0.f, pmax = 0.f;
        #pragma unroll
        for (int r = 0; r < 16; ++r) {
            const int CR = (r & 3) + 8 * (r >> 2);
            float q2 = fmaxf(D[r], 0.f);
            float P = __builtin_amdgcn_exp2f(-q2);
            float ser = fmaf(P * P, fmaf(P, 0.33333333f, 0.5f), P);
            bce_t += ser;
            pmax = fmaxf(pmax, P);
            ownP = (lb4 == CR) ? P : ownP;
        }
        // own-cluster correction: q_own = -ln(ownP); replace its series term
        float sero = fmaf(ownP * ownP, fmaf(ownP, 0.33333333f, 0.5f), ownP);
        float qown = -0.69314718f * __log2f(ownP);
        float ocorr = fminf(qown, 100.f) - sero;
        bce_t += hasown ? ocorr : 0.f;

        // rare exact path (any P near 1): recompute tile with true log
        if (__any(pmax > 0.70f)) {
            bce_t = 0.f;
            #pragma unroll
            for (int r = 0; r < 16; ++r) {
                const int CR = (r & 3) + 8 * (r >> 2);
                float q2 = fmaxf(D[r], 0.f);
                float P = __builtin_amdgcn_exp2f(-q2);
                float tw = fminf(-__logf(1.0f - P), 100.f);
                float to = fminf(q2 * 0.69314718f, 100.f);
                bce_t += (lb4 == CR) ? to : tw;
            }
        }

        float mask = ok ? 1.f : 0.f;
        bce = fmaf(mask, bce_t, bce);
        float e = ownP - s0;
        float smk = hasown ? mask : 0.f;
        sl = fmaf(smk * e, e, sl);
    }

    __shared__ float rb[256], rsd[256];
    rb[tid] = bce; rsd[tid] = sl;
    __syncthreads();
    for (int s = 128; s > 0; s >>= 1) {
        if (tid < s) { rb[tid] += rb[tid + s]; rsd[tid] += rsd[tid + s]; }
        __syncthreads();
    }
    if (tid == 0) {
        float2 pr; pr.x = rb[0]; pr.y = rsd[0];
        ((float2*)(ws + PMAIN))[blockIdx.x] = pr;
    }
}

__global__ __launch_bounds__(1024)
void k_final(const float* __restrict__ ws, float* __restrict__ out, int n)
{
    __shared__ float rb[1024], rs[1024];
    int tid = threadIdx.x;
    float2 p0 = ((const float2*)(ws + PMAIN))[tid];
    float2 p1 = ((const float2*)(ws + PMAIN))[tid + 1024];
    rb[tid] = p0.x + p1.x; rs[tid] = p0.y + p1.y;
    __syncthreads();
    for (int s = 512; s > 0; s >>= 1) {
        if (tid < s) { rb[tid] += rb[tid + s]; rs[tid] += rs[tid + s]; }
        __syncthreads();
    }
    if (tid == 0) {
        float var_loss  = rb[0] / ((float)n * (float)NCLU);
        float seed_loss = rs[0] / (float)n;
        out[0] = W_VAR * var_loss + ws[G_SMALL] + W_SEED * seed_loss;
    }
}

extern "C" void kernel_launch(void* const* d_in, const int* in_sizes, int n_in,
                              void* d_out, int out_size, void* d_ws, size_t ws_size,
                              hipStream_t stream)
{
    const float* feat = (const float*)d_in[0];
    const float* sd   = (const float*)d_in[1];
    const int*   lab  = (const int*)d_in[2];
    float* ws = (float*)d_ws;
    int n = in_sizes[2];

    k_seg  <<<NBS, 256,  0, stream>>>(feat, sd, lab, ws, n);
    k_red1 <<<152, 256,  0, stream>>>(ws);
    k_stats<<<1,   1024, 0, stream>>>(ws);
    k_main <<<NBM, 256,  0, stream>>>(feat, sd, lab, ws, n);
    k_final<<<1,   1024, 0, stream>>>(ws, (float*)d_out, n);
}